// Round 4
// baseline (2409.567 us; speedup 1.0000x reference)
//
#include <hip/hip_runtime.h>

#define T_STEPS 512
#define BATCH   64
#define IN_SZ   32
#define AD      32
#define INNER   256
#define PROJ    224
#define HID     512
#define SENTW   0x7F7F7F7Fu   // bf16 0x7F7F = 3.3e38; impossible for |h|<1 outputs
#define D0      32            // h0 ring depth (slots per batch-group)
#define D1      16            // h1 ring depth

typedef __attribute__((ext_vector_type(8))) short short8;
typedef __attribute__((ext_vector_type(4))) float f32x4;

static __device__ __forceinline__ unsigned short f2bf(float f) {
  unsigned int u = __float_as_uint(f);
  u += 0x7FFFu + ((u >> 16) & 1u);
  return (unsigned short)(u >> 16);
}
static __device__ __forceinline__ float sigmoidf_(float x) { return 1.f / (1.f + __expf(-x)); }
static __device__ __forceinline__ float tanhf_(float x) {
  float e = __expf(-2.f * fabsf(x));
  float r = (1.f - e) / (1.f + e);
  return x < 0.f ? -r : r;
}

// ---------------- kernel A: x = [relu(in_w@state+in_b) | emb[idx]] bf16, [t][b][256]
__global__ __launch_bounds__(256) void k_prep(
    const float* __restrict__ ws_in, const int* __restrict__ act_idx,
    const float* __restrict__ emb, const float* __restrict__ in_w,
    const float* __restrict__ in_b, unsigned short* __restrict__ x_bf)
{
  int t = blockIdx.x;
  int tid = threadIdx.x;
  __shared__ float st[BATCH * IN_SZ];
  __shared__ int ai[BATCH];
  for (int i = tid; i < BATCH * IN_SZ; i += 256) {
    int b = i >> 5, k = i & 31;
    st[i] = ws_in[((size_t)b * T_STEPS + t) * IN_SZ + k];
  }
  if (tid < BATCH) ai[tid] = act_idx[tid * T_STEPS + t];
  __syncthreads();
  if (tid < PROJ) {
    float w[IN_SZ];
    const float* wrow = in_w + tid * IN_SZ;
#pragma unroll
    for (int k = 0; k < IN_SZ; ++k) w[k] = wrow[k];
    float bb = in_b[tid];
    for (int b = 0; b < BATCH; ++b) {
      float acc = bb;
      const float* sb = st + b * IN_SZ;
#pragma unroll
      for (int k = 0; k < IN_SZ; ++k) acc += w[k] * sb[k];
      x_bf[((size_t)t * BATCH + b) * INNER + tid] = f2bf(fmaxf(acc, 0.f));
    }
  } else {
    int j = tid - PROJ;
    for (int b = 0; b < BATCH; ++b)
      x_bf[((size_t)t * BATCH + b) * INNER + tid] = f2bf(emb[ai[b] * AD + j]);
  }
}

// ---------------- helpers ----------------
static __device__ __forceinline__ short8 bfrag_load(const float* __restrict__ w, int stride, int row, int k0) {
  const float* p = w + (size_t)row * stride + k0;
  f32x4 a = *reinterpret_cast<const f32x4*>(p);
  f32x4 b = *reinterpret_cast<const f32x4*>(p + 4);
  short8 r;
  r[0] = (short)f2bf(a[0]); r[1] = (short)f2bf(a[1]); r[2] = (short)f2bf(a[2]); r[3] = (short)f2bf(a[3]);
  r[4] = (short)f2bf(b[0]); r[5] = (short)f2bf(b[1]); r[6] = (short)f2bf(b[2]); r[7] = (short)f2bf(b[3]);
  return r;
}

// h-slot word layout (4096 u32 words/slot): word(m,col) =
// ((m*4 + (col>>7))*4 + ((col>>3)&3))*16 + ((col>>5)&3)*4 + ((col>>1)&3)
// -> consumer lane (batch=ln, q), wave wv reads 16 CONSECUTIVE words = 64B = 4 MFMA k-chunks
static __device__ __forceinline__ int widx(int m, int col) {
  return ((m * 4 + (col >> 7)) * 4 + ((col >> 3) & 3)) * 16 + ((col >> 5) & 3) * 4 + ((col >> 1) & 3);
}

struct Frag64 { unsigned long long u[8]; };
union FU2 { unsigned long long u[2]; short8 s; };

static __device__ __forceinline__ bool ld_check(const unsigned int* p, Frag64& f) {
  const unsigned long long* q = reinterpret_cast<const unsigned long long*>(p);
#pragma unroll
  for (int i = 0; i < 8; ++i)
    f.u[i] = __hip_atomic_load(q + i, __ATOMIC_RELAXED, __HIP_MEMORY_SCOPE_AGENT);
  bool ok = true;
#pragma unroll
  for (int i = 0; i < 8; ++i)
    ok = ok & ((unsigned)(f.u[i] >> 32) != SENTW) & ((unsigned)f.u[i] != SENTW);
  return ok;
}

// spin until all 16 words this lane consumes are valid (data-as-flag)
static __device__ __forceinline__ Frag64 poll_frags(const unsigned int* p) {
  Frag64 f;
  int miss = 0;
  while (true) {
    bool ok = ld_check(p, f);
    if (__all((int)ok)) break;
    if (++miss > 4) __builtin_amdgcn_s_sleep(1);
  }
  return f;
}

static __device__ __forceinline__ void mfma4(const Frag64& f, const short8* wf, f32x4* acc) {
#pragma unroll
  for (int kk = 0; kk < 4; ++kk) {
    FU2 u; u.u[0] = f.u[kk * 2]; u.u[1] = f.u[kk * 2 + 1];
#pragma unroll
    for (int g = 0; g < 4; ++g)
      acc[g] = __builtin_amdgcn_mfma_f32_16x16x32_bf16(u.s, wf[g * 4 + kk], acc[g], 0, 0, 0);
  }
}

static __device__ __forceinline__ void st_agent(unsigned int* p, unsigned int v) {
  __hip_atomic_store(p, v, __ATOMIC_RELAXED, __HIP_MEMORY_SCOPE_AGENT);
}

// ---------------- persistent 2-layer LSTM ----------------
// 256 blocks; xg=blockIdx&7: layer=xg>=4, bg=xg&3; blk=blockIdx>>3 owns hid [blk*16,+16).
// Weights in VGPRs (bf16 B-frags, K/4 per wave); c in registers. h exchange: sentinel rings,
// ALL cross-block ops via __hip_atomic_* AGENT relaxed (LLC-coherent). Producers reset their
// own ring words mid-ring (+D/2); vmcnt(0) drain every 8 steps bounds reset visibility.
// L1 publishes progress flags every 8 steps; L0 guards ring reuse on them every 8 steps.
template<int L>
static __device__ void lstm_body(
    const unsigned short* __restrict__ x_bf,
    const float* __restrict__ wih, const float* __restrict__ whh,
    const float* __restrict__ bih, const float* __restrict__ bhh,
    unsigned int* __restrict__ h0w, unsigned int* __restrict__ h1w,
    float* __restrict__ h1fin, unsigned int* __restrict__ flags,
    int bg, int blk, float* __restrict__ spart)
{
  constexpr int KI = (L == 0) ? 2 : 4;

  const int tid  = threadIdx.x;
  const int lane = tid & 63;
  const int wv   = tid >> 6;
  const int q    = lane >> 4;
  const int ln   = lane & 15;
  const int hid0 = blk << 4;
  const int m    = tid >> 4;
  const int n    = tid & 15;
  const int lbase = ((ln * 4 + wv) * 4 + q) * 16;  // consumer 64B/lane word base in a slot

  float bias[4];
#pragma unroll
  for (int g = 0; g < 4; ++g)
    bias[g] = bih[g * HID + hid0 + n] + bhh[g * HID + hid0 + n];

  short8 fih[4 * KI];
#pragma unroll
  for (int g = 0; g < 4; ++g)
#pragma unroll
    for (int kk = 0; kk < KI; ++kk)
      fih[g * KI + kk] = bfrag_load(wih, (L == 0) ? INNER : HID,
                                    g * HID + hid0 + ln, (wv * KI + kk) * 32 + q * 8);
  short8 fhh[16];
#pragma unroll
  for (int g = 0; g < 4; ++g)
#pragma unroll
    for (int kk = 0; kk < 4; ++kk)
      fhh[g * 4 + kk] = bfrag_load(whh, HID, g * HID + hid0 + ln, (wv * 4 + kk) * 32 + q * 8);

  const int wo = (!(n & 1)) ? widx(m, hid0 + n) : 0;
  float c_state = 0.f;

  for (int t = 0; t < T_STEPS; ++t) {
    f32x4 acc[4];
#pragma unroll
    for (int g = 0; g < 4; ++g) acc[g] = (f32x4){0.f, 0.f, 0.f, 0.f};

    if constexpr (L == 0) {
      // ring-reuse guard vs layer 1 (every 8 steps): need L1 completed step t-9
      if ((t & 7) == 0 && t >= 16) {
        const unsigned int* fp = flags + bg * 32 + (lane & 31);
        unsigned int tgt = (unsigned)(t - 8);
        while (true) {
          unsigned int v = __hip_atomic_load(fp, __ATOMIC_RELAXED, __HIP_MEMORY_SCOPE_AGENT);
          if (__all((int)(v >= tgt))) break;
          __builtin_amdgcn_s_sleep(1);
        }
        asm volatile("" ::: "memory");
      }
      // x fragments: static data, plain cached loads
      const unsigned short* xr = x_bf + ((size_t)t * BATCH + bg * 16 + ln) * INNER + q * 8;
      short8 xa[KI];
#pragma unroll
      for (int kk = 0; kk < KI; ++kk)
        xa[kk] = *reinterpret_cast<const short8*>(xr + (wv * KI + kk) * 32);

      if (t > 0) {  // recurrent: data-poll h0[t-1]
        Frag64 f = poll_frags(h0w + (size_t)(bg * D0 + ((t - 1) & (D0 - 1))) * 4096 + lbase);
        mfma4(f, fhh, acc);
      }
#pragma unroll
      for (int kk = 0; kk < KI; ++kk)
#pragma unroll
        for (int g = 0; g < 4; ++g)
          acc[g] = __builtin_amdgcn_mfma_f32_16x16x32_bf16(xa[kk], fih[g * KI + kk], acc[g], 0, 0, 0);
    } else {
      if (t > 0) {  // recurrent: h1[t-1] (usually ready -> cheap)
        Frag64 f = poll_frags(h1w + (size_t)(bg * D1 + ((t - 1) & (D1 - 1))) * 4096 + lbase);
        mfma4(f, fhh, acc);
      }
      // input: h0[t] from layer 0
      Frag64 f = poll_frags(h0w + (size_t)(bg * D0 + (t & (D0 - 1))) * 4096 + lbase);
      mfma4(f, fih, acc);
    }

    // K-split partial exchange (XOR swizzle: conflict-free writes, 2-way-free reads)
    float* sp_w = spart + (t & 1) * 4096;
#pragma unroll
    for (int g = 0; g < 4; ++g)
#pragma unroll
      for (int r = 0; r < 4; ++r)
        sp_w[(((wv * 4 + g) * 4 + r) * 4 + (q ^ r)) * 16 + ln] = acc[g][r];
    __syncthreads();

    float gate[4];
#pragma unroll
    for (int g = 0; g < 4; ++g) {
      float s = bias[g];
#pragma unroll
      for (int w2 = 0; w2 < 4; ++w2)
        s += sp_w[(((w2 * 4 + g) * 4 + (m & 3)) * 4 + ((m >> 2) ^ (m & 3))) * 16 + n];
      gate[g] = s;
    }
    float gi = sigmoidf_(gate[0]);
    float gf = sigmoidf_(gate[1]);
    float gc = tanhf_(gate[2]);
    float go = sigmoidf_(gate[3]);
    c_state = gf * c_state + gi * gc;
    float h = go * tanhf_(c_state);

    // publish h (pack n-even|n-odd pair); reset mid-ring slot for future reuse
    float hp = __shfl_xor(h, 1);
    unsigned int wword = (unsigned)f2bf(h) | ((unsigned)f2bf(hp) << 16);
    if constexpr (L == 0) {
      if (!(n & 1)) {
        st_agent(h0w + (size_t)(bg * D0 + (t & (D0 - 1))) * 4096 + wo, wword);
        st_agent(h0w + (size_t)(bg * D0 + ((t + 16) & (D0 - 1))) * 4096 + wo, SENTW);
      }
      if ((t & 7) == 7) asm volatile("s_waitcnt vmcnt(0)" ::: "memory");
    } else {
      if (!(n & 1)) {
        st_agent(h1w + (size_t)(bg * D1 + (t & (D1 - 1))) * 4096 + wo, wword);
        st_agent(h1w + (size_t)(bg * D1 + ((t + 8) & (D1 - 1))) * 4096 + wo, SENTW);
      }
      if (t == T_STEPS - 1)
        h1fin[(size_t)(bg * 16 + m) * HID + hid0 + n] = h;
      if ((t & 7) == 7) {
        asm volatile("s_waitcnt vmcnt(0)" ::: "memory");
        if (tid == 0) st_agent(flags + bg * 32 + blk, (unsigned)(t + 1));
      }
    }
  }
}

__global__ __launch_bounds__(256, 1) void k_lstm(
    const unsigned short* __restrict__ x_bf,
    const float* __restrict__ w_ih0, const float* __restrict__ w_hh0,
    const float* __restrict__ b_ih0, const float* __restrict__ b_hh0,
    const float* __restrict__ w_ih1, const float* __restrict__ w_hh1,
    const float* __restrict__ b_ih1, const float* __restrict__ b_hh1,
    unsigned int* h0w, unsigned int* h1w, float* h1fin, unsigned int* flags)
{
  __shared__ float spart[2 * 4096];
  const int xg  = blockIdx.x & 7;
  const int blk = blockIdx.x >> 3;
  const int bg  = xg & 3;
  if (xg < 4)
    lstm_body<0>(x_bf, w_ih0, w_hh0, b_ih0, b_hh0, h0w, h1w, h1fin, flags, bg, blk, spart);
  else
    lstm_body<1>(x_bf, w_ih1, w_hh1, b_ih1, b_hh1, h0w, h1w, h1fin, flags, bg, blk, spart);
}

// ---------------- output head on final h1 (fp32) ----------------
__global__ __launch_bounds__(256) void k_head(
    const float* __restrict__ h1, const float* __restrict__ w1, const float* __restrict__ b1,
    const float* __restrict__ w2, const float* __restrict__ b2, float* __restrict__ out)
{
  int b = blockIdx.x, tid = threadIdx.x;
  __shared__ float sh[HID];
  __shared__ float sm[2 * HID];
  for (int k = tid; k < HID; k += 256) sh[k] = h1[(size_t)b * HID + k];
  __syncthreads();
#pragma unroll
  for (int r0 = 0; r0 < 4; ++r0) {
    int row = r0 * 256 + tid;
    const f32x4* wr = reinterpret_cast<const f32x4*>(w1 + (size_t)row * HID);
    float s = 0.f;
#pragma unroll 4
    for (int k = 0; k < HID / 4; ++k) {
      f32x4 v = wr[k];
      s += v[0] * sh[k * 4] + v[1] * sh[k * 4 + 1] + v[2] * sh[k * 4 + 2] + v[3] * sh[k * 4 + 3];
    }
    sm[row] = fmaxf(b1[row] + s, 0.f);
  }
  __syncthreads();
  if (tid < 32) {
    const f32x4* wr = reinterpret_cast<const f32x4*>(w2 + (size_t)tid * 2 * HID);
    float s = b2[tid];
#pragma unroll 4
    for (int k = 0; k < 2 * HID / 4; ++k) {
      f32x4 v = wr[k];
      s += v[0] * sm[k * 4] + v[1] * sm[k * 4 + 1] + v[2] * sm[k * 4 + 2] + v[3] * sm[k * 4 + 3];
    }
    if (tid >= 24) s = sigmoidf_(s);   // CAT_FLAGS[24:]
    out[b * 32 + tid] = s;
  }
}

extern "C" void kernel_launch(void* const* d_in, const int* in_sizes, int n_in,
                              void* d_out, int out_size, void* d_ws, size_t ws_size,
                              hipStream_t stream) {
  const float* ws_in  = (const float*)d_in[0];
  const int*   aidx   = (const int*)d_in[1];
  const float* emb    = (const float*)d_in[2];
  const float* in_w   = (const float*)d_in[3];
  const float* in_b   = (const float*)d_in[4];
  const float* w_ih0  = (const float*)d_in[5];
  const float* w_hh0  = (const float*)d_in[6];
  const float* b_ih0  = (const float*)d_in[7];
  const float* b_hh0  = (const float*)d_in[8];
  const float* w_ih1  = (const float*)d_in[9];
  const float* w_hh1  = (const float*)d_in[10];
  const float* b_ih1  = (const float*)d_in[11];
  const float* b_hh1  = (const float*)d_in[12];
  const float* out_w1 = (const float*)d_in[13];
  const float* out_b1 = (const float*)d_in[14];
  const float* out_w2 = (const float*)d_in[15];
  const float* out_b2 = (const float*)d_in[16];

  unsigned char* ws = (unsigned char*)d_ws;
  const size_t X_OFF  = 0;                         // 16,777,216
  const size_t H0_OFF = 16777216;                  // 4bg*32slots*16KB = 2,097,152
  const size_t H1_OFF = H0_OFF + 2097152;          // 4bg*16slots*16KB = 1,048,576
  const size_t HF_OFF = H1_OFF + 1048576;          // h1fin 131,072
  const size_t FL_OFF = HF_OFF + 131072;           // flags 1,024
  unsigned short* x_bf  = (unsigned short*)(ws + X_OFF);
  unsigned int*   h0w   = (unsigned int*)(ws + H0_OFF);
  unsigned int*   h1w   = (unsigned int*)(ws + H1_OFF);
  float*          h1fin = (float*)(ws + HF_OFF);
  unsigned int*   flags = (unsigned int*)(ws + FL_OFF);

  hipMemsetAsync(ws + H0_OFF, 0x7F, 2097152 + 1048576, stream);  // h rings -> sentinel
  hipMemsetAsync(ws + FL_OFF, 0, 1024, stream);
  k_prep<<<dim3(T_STEPS), dim3(256), 0, stream>>>(ws_in, aidx, emb, in_w, in_b, x_bf);
  k_lstm<<<dim3(256), dim3(256), 0, stream>>>(x_bf, w_ih0, w_hh0, b_ih0, b_hh0,
                                              w_ih1, w_hh1, b_ih1, b_hh1,
                                              h0w, h1w, h1fin, flags);
  k_head<<<dim3(BATCH), dim3(256), 0, stream>>>(h1fin, out_w1, out_b1, out_w2, out_b2, (float*)d_out);
}